// Round 6
// baseline (352.632 us; speedup 1.0000x reference)
//
#include <hip/hip_runtime.h>
#include <math.h>

// B=32, C=256, GROUPS=8 -> bg=256 group-batches, cg=32 channels, 64x64 planes
#define PLANE 4096

__device__ __forceinline__ float sigm(float v){ return 1.0f/(1.0f+expf(-v)); }

// ---------------- Prep: x11=softmax(gn_b) (data-independent), wc[i][9]=sum_c x11*w3,
//                  cb = x11·b3, w1T[i*32+o], w3T[(i*9+k)*32+c] ----------------
__global__ __launch_bounds__(256) void kPrep(const float* __restrict__ gn_b,
    const float* __restrict__ w1, const float* __restrict__ w3,
    const float* __restrict__ b3,
    float* __restrict__ wcg, float* __restrict__ cbg,
    float* __restrict__ w1T, float* __restrict__ w3T){
  __shared__ float x11[32];
  const int t=threadIdx.x;
  if(t==0){
    float m=-1e30f;
    #pragma unroll
    for(int c=0;c<32;++c) m=fmaxf(m,gn_b[c]);
    float e[32]; float s=0.f;
    #pragma unroll
    for(int c=0;c<32;++c){ e[c]=expf(gn_b[c]-m); s+=e[c]; }
    const float inv=1.f/s;
    float cb=0.f;
    #pragma unroll
    for(int c=0;c<32;++c){ x11[c]=e[c]*inv; cb+=x11[c]*b3[c]; }
    *cbg=cb;
  }
  __syncthreads();
  for(int idx=t; idx<288; idx+=256){
    const int i=idx/9, k=idx%9;
    float s=0.f;
    #pragma unroll
    for(int c=0;c<32;++c) s += x11[c]*w3[(c*32+i)*9+k];
    wcg[idx]=s;
  }
  for(int idx=t; idx<1024; idx+=256) w1T[idx] = w1[(idx&31)*32 + (idx>>5)];
  for(int idx=t; idx<9216; idx+=256){
    const int c=idx&31, r=idx>>5, i=r/9, k=r-9*i;
    w3T[idx] = w3[(c*32+i)*9+k];
  }
}

// ---------------- Fused: one block per b; phases in LDS ----------------
// LDS layout (floats):
//  SW 0..2048 | WCS 2048..2336 | ALPH 2336..2368 | MUS 2400..2432 | SQS 2432..2464
//  CST 2464 | unionA from 2468: {MARG 32x132=4224 -> 6692 | W1S 1024 -> 7716 |
//  S 288 -> 8004 | CORN 128 -> 8132 | SH 2048 -> 10180}  overlaid by
//  H 3*66*68=13464 -> 15932 (written only after SH copied to regs)
#define TB 1024
__global__ __launch_bounds__(TB, 4) void kFused(const float* __restrict__ x,
    const float* __restrict__ b1, const float* __restrict__ b3,
    const float* __restrict__ gn_w, const float* __restrict__ gn_b,
    const float* __restrict__ wc, const float* __restrict__ cb,
    const float* __restrict__ w1T, const float* __restrict__ w3T,
    float* __restrict__ out){
  const int b = blockIdx.x;
  const int t = threadIdx.x;
  __shared__ float L[15936];
  float* SW   = L;
  float* WCS  = L+2048;
  float* ALPH = L+2336;
  float* MUS  = L+2400;
  float* SQS  = L+2432;
  float* CST  = L+2464;
  float* MARG = L+2468;
  float* W1S  = L+6692;   // w1T, later reused as red[256]
  float* S    = L+7716;
  float* CORN = L+8004;
  float* SH   = L+8132;
  float* Hb   = L+2468;   // overlays MARG..SH after prologue

  const float* __restrict__ xb = x + (size_t)b*32*PLANE;

  for(int idx=t; idx<288; idx+=TB) WCS[idx]=wc[idx];
  for(int idx=t; idx<1024; idx+=TB) W1S[idx]=w1T[idx];

  // ---- phase 0a: per-plane row sums, col sums, corners (group i = t>>5) ----
  {
    const int i = t>>5, j = t&31;
    const float* __restrict__ p = xb + (size_t)i*PLANE + j*4;
    float ca0=0.f, ca1=0.f, ca2=0.f, ca3=0.f;
    #pragma unroll
    for(int ch=0; ch<4; ++ch){
      float4 v[8];
      #pragma unroll
      for(int k=0;k<8;++k) v[k] = *reinterpret_cast<const float4*>(p + (ch*8+k)*128);
      #pragma unroll
      for(int k=0;k<8;++k){
        const int s = ch*8+k;                 // global step; rows 2s, 2s+1
        float rp = v[k].x+v[k].y+v[k].z+v[k].w;
        rp += __shfl_xor(rp,1,64); rp += __shfl_xor(rp,2,64);
        rp += __shfl_xor(rp,4,64); rp += __shfl_xor(rp,8,64);
        if((j&15)==0) MARG[i*132 + 2*s + (j>>4)] = rp;   // raw row sum
        ca0+=v[k].x; ca1+=v[k].y; ca2+=v[k].z; ca3+=v[k].w;
        if(ch==0&&k==0){ if(j==0)  CORN[i*4+0]=v[k].x;   // (0,0)
                         if(j==15) CORN[i*4+1]=v[k].w; } // (0,63)
        if(ch==3&&k==7){ if(j==16) CORN[i*4+2]=v[k].x;   // (63,0)
                         if(j==31) CORN[i*4+3]=v[k].w; } // (63,63)
      }
    }
    ca0+=__shfl_xor(ca0,16,64); ca1+=__shfl_xor(ca1,16,64);
    ca2+=__shfl_xor(ca2,16,64); ca3+=__shfl_xor(ca3,16,64);
    if(j<16) *reinterpret_cast<float4*>(&MARG[i*132+64+4*j]) =
        make_float4(ca0,ca1,ca2,ca3);                    // raw col sums
  }
  __syncthreads();

  // ---- phase 0b: sh/sw = sigmoid(w1 @ [rowmean;colmean] + b1) ----
  {
    const int o = t>>5;
    const int p0 = (t&31)*4;                 // 4 consecutive positions in [0,128)
    float a0=0.f,a1=0.f,a2=0.f,a3=0.f;
    #pragma unroll
    for(int i=0;i<32;++i){
      const float w = W1S[i*32+o];           // broadcast per 32-group
      const float4 mv = *reinterpret_cast<const float4*>(&MARG[i*132+p0]);
      a0+=w*mv.x; a1+=w*mv.y; a2+=w*mv.z; a3+=w*mv.w;
    }
    const float bo = b1[o];
    const float inv64 = 1.0f/64.0f;
    float4 r;
    r.x=sigm(bo+a0*inv64); r.y=sigm(bo+a1*inv64);
    r.z=sigm(bo+a2*inv64); r.w=sigm(bo+a3*inv64);
    if(p0<64) *reinterpret_cast<float4*>(&SH[o*64+p0])      = r;
    else      *reinterpret_cast<float4*>(&SW[o*64+p0-64])   = r;
  }
  __syncthreads();

  // ---- phase 1: gated stats per plane (group i = t>>5) ----
  {
    const int i = t>>5, j = t&31;
    const float* __restrict__ p = xb + (size_t)i*PLANE + j*4;
    const float4 swv = *reinterpret_cast<const float4*>(&SW[i*64+(j&15)*4]);
    float s=0.f, q=0.f;
    #pragma unroll
    for(int ch=0; ch<4; ++ch){
      float4 v[8];
      #pragma unroll
      for(int k=0;k<8;++k) v[k] = *reinterpret_cast<const float4*>(p + (ch*8+k)*128);
      #pragma unroll
      for(int k=0;k<8;++k){
        const int srow = 2*(ch*8+k) + (j>>4);
        const float a = SH[i*64+srow];
        const float g0=v[k].x*a*swv.x, g1=v[k].y*a*swv.y;
        const float g2=v[k].z*a*swv.z, g3=v[k].w*a*swv.w;
        s += g0+g1+g2+g3;
        q += g0*g0+g1*g1+g2*g2+g3*g3;
      }
    }
    s+=__shfl_xor(s,1,64); s+=__shfl_xor(s,2,64); s+=__shfl_xor(s,4,64);
    s+=__shfl_xor(s,8,64); s+=__shfl_xor(s,16,64);
    q+=__shfl_xor(q,1,64); q+=__shfl_xor(q,2,64); q+=__shfl_xor(q,4,64);
    q+=__shfl_xor(q,8,64); q+=__shfl_xor(q,16,64);
    if(j==0){ MUS[i]=s; SQS[i]=q; }
    // region sums S[i][ky*3+kx] for conv-mean (threads 0-31, done here: reads MARG)
    if(t<32){
      const int ii=t;
      float Ti=0.f;
      for(int h=0;h<64;++h) Ti += MARG[ii*132+h];
      const float r0=MARG[ii*132+0],  r63=MARG[ii*132+63];
      const float c0s=MARG[ii*132+64], c63s=MARG[ii*132+127];
      const float k00=CORN[ii*4+0], k01=CORN[ii*4+1];
      const float k10=CORN[ii*4+2], k11=CORN[ii*4+3];
      #pragma unroll
      for(int ky=0;ky<3;++ky){
        #pragma unroll
        for(int kx=0;kx<3;++kx){
          float ss=Ti;
          if(ky==0) ss-=r63; else if(ky==2) ss-=r0;
          if(kx==0) ss-=c63s; else if(kx==2) ss-=c0s;
          if(ky==0&&kx==0) ss+=k11;
          if(ky==0&&kx==2) ss+=k10;
          if(ky==2&&kx==0) ss+=k01;
          if(ky==2&&kx==2) ss+=k00;
          S[ii*9+ky*3+kx]=ss;
        }
      }
    }
  }
  __syncthreads();

  // ---- phase 0c: mean(x2) matvec partials (coalesced w3T reads) ----
  if(t<256){
    const int c = t&31, chunk = t>>5;
    float part = 0.f;
    #pragma unroll
    for(int ii=0; ii<4; ++ii){
      const int i = chunk*4+ii;
      #pragma unroll
      for(int k=0;k<9;++k) part += w3T[(i*9+k)*32+c]*S[i*9+k];
    }
    W1S[t] = part;                 // red[256] reuse
  }
  __syncthreads();
  // x21 softmax + alphas + constsh (threads 0-31)
  if(t<32){
    float mm=0.f;
    #pragma unroll
    for(int ch=0;ch<8;++ch) mm += W1S[ch*32+t];
    mm = mm*(1.0f/4096.0f) + b3[t];
    float mx = mm;
    #pragma unroll
    for(int s2=1;s2<32;s2<<=1) mx = fmaxf(mx, __shfl_xor(mx,s2,64));
    const float e = expf(mm-mx);
    float ss = e;
    #pragma unroll
    for(int s2=1;s2<32;s2<<=1) ss += __shfl_xor(ss,s2,64);
    const float xv = e/ss;                       // x21[b][t]
    const float ms = MUS[t]*(1.0f/4096.0f);
    const float vv = SQS[t]*(1.0f/4096.0f) - ms*ms;
    const float rq = rsqrtf(vv + 1e-5f);
    ALPH[t] = xv*gn_w[t]*rq;
    float part2 = xv*(gn_b[t] - gn_w[t]*rq*ms);
    #pragma unroll
    for(int s2=1;s2<32;s2<<=1) part2 += __shfl_xor(part2,s2,64);
    if(t==0) CST[0] = part2 + cb[0];
  }
  __syncthreads();

  // ---- phase 2 prologue: fold alphas*sh into registers (frees SH for H) ----
  const int row = t>>4;                   // 0..63
  const int c0  = (t&15)<<2;              // 0..60
  float ashr[32];
  #pragma unroll
  for(int i=0;i<32;++i) ashr[i] = ALPH[i]*SH[i*64+row];
  __syncthreads();                        // SH/MARG/W1S/S/CORN all dead now

  // zero H pad rows (map rows 0 and 65 of each ky map)
  if(t<102){
    const int m=t/34, rr=((t%34)/17)*65, cc=(t%17)*4;
    *reinterpret_cast<float4*>(&Hb[m*4488 + rr*68 + cc]) = make_float4(0.f,0.f,0.f,0.f);
  }

  // ---- phase 2: channel loop — register tap accumulation, no barriers ----
  float acc[4][9];
  float gacc[4];
  #pragma unroll
  for(int jj=0;jj<4;++jj){
    gacc[jj]=0.f;
    #pragma unroll
    for(int k=0;k<9;++k) acc[jj][k]=0.f;
  }
  {
    const float* __restrict__ px = xb + row*64 + c0;
    #pragma unroll 4
    for(int i=0;i<32;++i){
      const float4 v = *reinterpret_cast<const float4*>(px + (size_t)i*PLANE);
      const float4 swv = *reinterpret_cast<const float4*>(&SW[i*64+c0]);
      const float* __restrict__ wq = &WCS[i*9];
      const float ash = ashr[i];
      const float vv0=v.x, vv1=v.y, vv2=v.z, vv3=v.w;
      #pragma unroll
      for(int k=0;k<9;++k){
        const float w = wq[k];
        acc[0][k] += w*vv0; acc[1][k] += w*vv1;
        acc[2][k] += w*vv2; acc[3][k] += w*vv3;
      }
      gacc[0] += ash*swv.x*vv0; gacc[1] += ash*swv.y*vv1;
      gacc[2] += ash*swv.z*vv2; gacc[3] += ash*swv.w*vv3;
    }
  }
  // horizontal 3-tap combine -> H maps (plane row r stored at map row r+1)
  #pragma unroll
  for(int ky=0;ky<3;++ky){
    float lf = __shfl_up(acc[3][ky*3+0], 1);
    float rt = __shfl_down(acc[0][ky*3+2], 1);
    if(c0==0)  lf = 0.f;
    if(c0==60) rt = 0.f;
    const float h0 = lf             + acc[0][ky*3+1] + acc[1][ky*3+2];
    const float h1 = acc[0][ky*3+0] + acc[1][ky*3+1] + acc[2][ky*3+2];
    const float h2 = acc[1][ky*3+0] + acc[2][ky*3+1] + acc[3][ky*3+2];
    const float h3 = acc[2][ky*3+0] + acc[3][ky*3+1] + rt;
    *reinterpret_cast<float4*>(&Hb[ky*4488 + (row+1)*68 + c0]) =
        make_float4(h0,h1,h2,h3);
  }
  __syncthreads();

  // ---- vertical combine + sigmoid + fused output ----
  {
    const float4 h0 = *reinterpret_cast<const float4*>(&Hb[0*4488 + (row  )*68 + c0]);
    const float4 h1 = *reinterpret_cast<const float4*>(&Hb[1*4488 + (row+1)*68 + c0]);
    const float4 h2 = *reinterpret_cast<const float4*>(&Hb[2*4488 + (row+2)*68 + c0]);
    const float cst = CST[0];
    const float wf0 = 1.f + sigm(h0.x+h1.x+h2.x + gacc[0] + cst);
    const float wf1 = 1.f + sigm(h0.y+h1.y+h2.y + gacc[1] + cst);
    const float wf2 = 1.f + sigm(h0.z+h1.z+h2.z + gacc[2] + cst);
    const float wf3 = 1.f + sigm(h0.w+h1.w+h2.w + gacc[3] + cst);
    const float* __restrict__ px = xb + row*64 + c0;
    float*       __restrict__ po = out + (size_t)b*32*PLANE + row*64 + c0;
    #pragma unroll 4
    for(int i=0;i<32;++i){
      const float4 v = *reinterpret_cast<const float4*>(px + (size_t)i*PLANE);
      float4 o;
      o.x=v.x*wf0; o.y=v.y*wf1; o.z=v.z*wf2; o.w=v.w*wf3;
      *reinterpret_cast<float4*>(po + (size_t)i*PLANE) = o;
    }
  }
}

extern "C" void kernel_launch(void* const* d_in, const int* in_sizes, int n_in,
                              void* d_out, int out_size, void* d_ws, size_t ws_size,
                              hipStream_t stream){
  (void)in_sizes; (void)n_in; (void)out_size; (void)ws_size;
  const float* x    = (const float*)d_in[0];
  const float* w1   = (const float*)d_in[1];
  const float* b1   = (const float*)d_in[2];
  const float* w3   = (const float*)d_in[3];
  const float* b3   = (const float*)d_in[4];
  const float* gn_w = (const float*)d_in[5];
  const float* gn_b = (const float*)d_in[6];
  float* out = (float*)d_out;
  float* ws  = (float*)d_ws;

  float* wc  = ws + 0;      // 288
  float* cb  = ws + 288;    // 1
  float* w1T = ws + 320;    // 1024
  float* w3T = ws + 1344;   // 9216

  kPrep <<<1,   256, 0, stream>>>(gn_b, w1, w3, b3, wc, cb, w1T, w3T);
  kFused<<<256, TB,  0, stream>>>(x, b1, b3, gn_w, gn_b, wc, cb, w1T, w3T, out);
}